// Round 2
// baseline (1527.995 us; speedup 1.0000x reference)
//
#include <hip/hip_runtime.h>
#include <hip/hip_bf16.h>
#include <math.h>

#define S_LEN 512
#define B_SZ  256
#define I_SZ  227
#define H_SZ  100
#define T_SZ  19

__device__ __forceinline__ float tanh_fast(float x) {
    // tanh(x) = 1 - 2/(exp(2x)+1); exp overflow -> inf -> 1, underflow -> -1. OK.
    float e = __expf(2.0f * x);
    return 1.0f - 2.0f / (e + 1.0f);
}

// ---------------------------------------------------------------------------
// K1: input projection. xf[s,b,j] = x[s,b,:]·w_ih_f[j,:] + b_ih_f[j], xb same.
//     64 rows staged in LDS (rows padded to 232 floats -> aligned b128 reads).
//     Wave q owns j in [50q,50q+50): w rows via wave-uniform ptrs (s_load).
//     Results held in regs (acc[5][10]), then LDS-staged coalesced f4 stores.
// ---------------------------------------------------------------------------
#define LXPAD 232
__global__ __launch_bounds__(256, 2)
void k1_inproj(const float* __restrict__ x,
               const float* __restrict__ w_ih_f, const float* __restrict__ b_ih_f,
               const float* __restrict__ w_ih_b, const float* __restrict__ b_ih_b,
               float* __restrict__ xf, float* __restrict__ xb) {
    __shared__ float lx[64 * LXPAD];        // 59.4 KB; also reused as lout (12800 fl)
    const int tid  = threadIdx.x;
    const int lane = tid & 63;
    const long m0  = (long)blockIdx.x * 64;

    {   // stage x rows [m0, m0+64) x [0,227): col-groups 57,57,57,56 per wave
        const int cg = tid >> 6;
        const int c0 = cg * 57;
        const int nc = (cg == 3) ? 56 : 57;
        const float* src = x + (m0 + lane) * I_SZ;
        float* dst = lx + lane * LXPAD;
        for (int i = 0; i < nc; ++i) dst[c0 + i] = src[c0 + i];
    }
    __syncthreads();

    const int jb = __builtin_amdgcn_readfirstlane(tid >> 6) * 50;   // uniform
    const float* xrow = lx + lane * LXPAD;

    float acc[5][10];
    #pragma unroll
    for (int g = 0; g < 5; ++g) {
        const int j0 = jb + g * 10;         // uniform; never crosses j=100
        const float* wr[10];
        #pragma unroll
        for (int u = 0; u < 10; ++u) {
            int j = j0 + u;
            if (j < 100) { wr[u] = w_ih_f + (long)j * I_SZ;         acc[g][u] = b_ih_f[j]; }
            else         { wr[u] = w_ih_b + (long)(j - 100) * I_SZ; acc[g][u] = b_ih_b[j - 100]; }
        }
        for (int k = 0; k < 224; k += 4) {
            float4 xv = *(const float4*)(xrow + k);
            #pragma unroll
            for (int u = 0; u < 10; ++u) {
                acc[g][u] = fmaf(xv.x, wr[u][k],     acc[g][u]);
                acc[g][u] = fmaf(xv.y, wr[u][k + 1], acc[g][u]);
                acc[g][u] = fmaf(xv.z, wr[u][k + 2], acc[g][u]);
                acc[g][u] = fmaf(xv.w, wr[u][k + 3], acc[g][u]);
            }
        }
        #pragma unroll
        for (int k = 224; k < 227; ++k) {
            float xv = xrow[k];
            #pragma unroll
            for (int u = 0; u < 10; ++u) acc[g][u] = fmaf(xv, wr[u][k], acc[g][u]);
        }
    }

    __syncthreads();                         // all lx reads done; reuse as lout
    #pragma unroll
    for (int g = 0; g < 5; ++g) {
        #pragma unroll
        for (int u = 0; u < 10; ++u) {
            int j = jb + g * 10 + u;
            int base = (j < 100) ? (lane * 100 + j) : (6400 + lane * 100 + (j - 100));
            lx[base] = acc[g][u];
        }
    }
    __syncthreads();

    float* dstf = xf + m0 * 100;             // block regions are contiguous
    float* dstb = xb + m0 * 100;
    for (int i = tid; i < 1600; i += 256) {
        ((float4*)dstf)[i] = ((const float4*)lx)[i];
        ((float4*)dstb)[i] = ((const float4*)(lx + 6400))[i];
    }
}

// ---------------------------------------------------------------------------
// K2: Elman RNN scan, both dirs. One block per (b,dir); 128 thr (j = tid).
//     Replicated-h: every lane FMAs the shared h vector (wave-uniform float4
//     LDS broadcasts) against its private W_hh row held in VGPRs (104 regs,
//     zero-padded). h written in-place over xproj. One barrier per step.
// ---------------------------------------------------------------------------
#define HPAD 104
__global__ __launch_bounds__(128, 1)
void k2_rnn(const float* __restrict__ w_hh_f, const float* __restrict__ b_hh_f,
            const float* __restrict__ w_hh_b, const float* __restrict__ b_hh_b,
            float* __restrict__ xf, float* __restrict__ xb) {
    __shared__ float hbuf[2][HPAD];
    const int tid = threadIdx.x;             // j = tid, valid < 100
    const int j   = tid;
    const int b   = blockIdx.x & 255;
    const int dir = blockIdx.x >> 8;

    const float* whh = dir ? w_hh_b : w_hh_f;
    const float* bhh = dir ? b_hh_b : b_hh_f;
    float* xp        = dir ? xb : xf;

    float wreg[HPAD];
    #pragma unroll
    for (int k = 0; k < HPAD; ++k) wreg[k] = 0.f;
    float bias = 0.f;
    if (j < 100) {
        bias = bhh[j];
        #pragma unroll
        for (int k = 0; k < 100; ++k) wreg[k] = whh[j * 100 + k];
    }
    if (tid < HPAD) { hbuf[0][tid] = 0.f; hbuf[1][tid] = 0.f; }
    __syncthreads();

    const int jj = (j < 100) ? j : 0;        // clamped addr for idle lanes
    float cur = xp[((long)(dir ? S_LEN - 1 : 0) * B_SZ + b) * 100 + jj];

    int p = 0;
    for (int t = 0; t < S_LEN; ++t) {
        const int s  = dir ? (S_LEN - 1 - t) : t;
        const int t2 = (t + 1 < S_LEN) ? (t + 1) : t;
        const int sn = dir ? (S_LEN - 1 - t2) : t2;
        float nxt = xp[((long)sn * B_SZ + b) * 100 + jj];    // prefetch

        float a0 = bias, a1 = 0.f, a2 = 0.f, a3 = 0.f;
        #pragma unroll
        for (int kk = 0; kk < 26; ++kk) {
            float4 hv = *(const float4*)&hbuf[p][kk * 4];    // uniform -> broadcast
            a0 = fmaf(wreg[4 * kk],     hv.x, a0);
            a1 = fmaf(wreg[4 * kk + 1], hv.y, a1);
            a2 = fmaf(wreg[4 * kk + 2], hv.z, a2);
            a3 = fmaf(wreg[4 * kk + 3], hv.w, a3);
        }
        float hval = tanh_fast(cur + ((a0 + a1) + (a2 + a3)));
        if (j < 100) {
            xp[((long)s * B_SZ + b) * 100 + j] = hval;       // in-place h
            hbuf[p ^ 1][j] = hval;
        }
        __syncthreads();
        p ^= 1;
        cur = nxt;
    }
}

// ---------------------------------------------------------------------------
// K4: emissions[s,b,t] = [hf|hb]·W_tag[t,:] + b_tag[t].
//     W_tag (15.2 KB) staged in LDS, read wave-uniform (broadcast). Each
//     thread reads its own h row as aligned float4 (L1/L3-absorbed), computes
//     5 tags, stages block's 64x19 tile in LDS, coalesced f4 stores.
// ---------------------------------------------------------------------------
__global__ __launch_bounds__(256, 4)
void k4_emis(const float* __restrict__ hf, const float* __restrict__ hb,
             const float* __restrict__ W_tag, const float* __restrict__ b_tag,
             float* __restrict__ em) {
    __shared__ float lw[T_SZ * 200];        // 15.2 KB
    __shared__ float lout[64 * T_SZ];       // 4.9 KB
    const int tid = threadIdx.x;
    const long m0 = (long)blockIdx.x * 64;

    for (int i = tid; i < 950; i += 256)    // 3800 floats = 950 float4
        ((float4*)lw)[i] = ((const float4*)W_tag)[i];
    __syncthreads();

    const int r  = tid & 63;
    const int tg = __builtin_amdgcn_readfirstlane(tid >> 6);  // uniform 0..3
    const float* hfr = hf + (m0 + r) * 100;  // 400B-aligned -> float4 ok
    const float* hbr = hb + (m0 + r) * 100;

    float acc[5];
    #pragma unroll
    for (int u = 0; u < 5; ++u) {
        int t = tg + 4 * u;
        acc[u] = (t < T_SZ) ? b_tag[t] : 0.f;
    }
    for (int k = 0; k < 100; k += 4) {
        float4 hv = *(const float4*)(hfr + k);
        float4 gv = *(const float4*)(hbr + k);
        #pragma unroll
        for (int u = 0; u < 5; ++u) {
            int t = tg + 4 * u;
            if (t < T_SZ) {
                float4 wv = *(const float4*)&lw[t * 200 + k];        // broadcast
                float4 vv = *(const float4*)&lw[t * 200 + 100 + k];  // broadcast
                acc[u] = fmaf(hv.x, wv.x, acc[u]); acc[u] = fmaf(hv.y, wv.y, acc[u]);
                acc[u] = fmaf(hv.z, wv.z, acc[u]); acc[u] = fmaf(hv.w, wv.w, acc[u]);
                acc[u] = fmaf(gv.x, vv.x, acc[u]); acc[u] = fmaf(gv.y, vv.y, acc[u]);
                acc[u] = fmaf(gv.z, vv.z, acc[u]); acc[u] = fmaf(gv.w, vv.w, acc[u]);
            }
        }
    }
    #pragma unroll
    for (int u = 0; u < 5; ++u) {
        int t = tg + 4 * u;
        if (t < T_SZ) lout[r * T_SZ + t] = acc[u];
    }
    __syncthreads();

    float* dst = em + m0 * T_SZ;             // contiguous 1216 floats = 304 f4
    for (int i = tid; i < 304; i += 256)
        ((float4*)dst)[i] = ((const float4*)lout)[i];
}

// ---------------------------------------------------------------------------
// K5: CRF numerator per batch. One 64-thr block per b.
// ---------------------------------------------------------------------------
__global__ __launch_bounds__(64)
void k5_numer(const int* __restrict__ tags, const float* __restrict__ em,
              const float* __restrict__ trans, const float* __restrict__ start_t,
              const float* __restrict__ end_t, float* __restrict__ num) {
    const int b   = blockIdx.x;
    const int tid = threadIdx.x;
    float acc = 0.f;
    #pragma unroll
    for (int i = 0; i < 8; ++i) {
        int s  = tid + i * 64;
        int ts = tags[(long)s * B_SZ + b];
        acc += em[((long)s * B_SZ + b) * T_SZ + ts];
        if (s < S_LEN - 1) {
            int tn = tags[(long)(s + 1) * B_SZ + b];
            acc += trans[ts * T_SZ + tn];
        }
    }
    if (tid == 0)  acc += start_t[tags[b]];
    if (tid == 63) acc += end_t[tags[(long)(S_LEN - 1) * B_SZ + b]];
    #pragma unroll
    for (int off = 32; off; off >>= 1) acc += __shfl_down(acc, off, 64);
    if (tid == 0) num[b] = acc;
}

// ---------------------------------------------------------------------------
// K6: CRF forward DP + final reduce. 1 wave/block, 3 batches/wave (lanes
//     (bl,j), 57 active). texp[i]=exp(trans[i][j]) in VGPRs. Double-buffered
//     score rows -> ONE barrier per step; per-lane local exps; max3 tree.
// ---------------------------------------------------------------------------
__global__ __launch_bounds__(64)
void k6_crf(const float* __restrict__ em, const float* __restrict__ trans,
            const float* __restrict__ start_t, const float* __restrict__ end_t,
            const float* __restrict__ num, float* __restrict__ out) {
    __shared__ float sbuf[2][3][20];        // rows 80B -> f4-aligned
    const int tid = threadIdx.x;
    const int bl  = tid / T_SZ;             // 0..2 for tid<57
    const int j   = tid - bl * T_SZ;
    const int b   = blockIdx.x * 3 + bl;
    const bool act = (tid < 57) && (b < B_SZ);

    float texp[T_SZ];
    float score = 0.f, em_cur = 0.f;
    if (act) {
        #pragma unroll
        for (int i = 0; i < T_SZ; ++i) texp[i] = __expf(trans[i * T_SZ + j]);
        score  = start_t[j] + em[(long)b * T_SZ + j];            // s=0
        em_cur = em[((long)1 * B_SZ + b) * T_SZ + j];            // prefetch s=1
    }

    int buf = 0;
    for (int s = 1; s < S_LEN; ++s) {
        float em_nxt = 0.f;
        if (act) {
            int sn = (s + 1 < S_LEN) ? (s + 1) : s;
            em_nxt = em[((long)sn * B_SZ + b) * T_SZ + j];       // prefetch
            sbuf[buf][bl][j] = score;
        }
        __syncthreads();
        if (act) {
            float4 v0 = *(const float4*)&sbuf[buf][bl][0];
            float4 v1 = *(const float4*)&sbuf[buf][bl][4];
            float4 v2 = *(const float4*)&sbuf[buf][bl][8];
            float4 v3 = *(const float4*)&sbuf[buf][bl][12];
            float4 v4 = *(const float4*)&sbuf[buf][bl][16];      // .w unused
            float sc[T_SZ] = {v0.x,v0.y,v0.z,v0.w, v1.x,v1.y,v1.z,v1.w,
                              v2.x,v2.y,v2.z,v2.w, v3.x,v3.y,v3.z,v3.w,
                              v4.x,v4.y,v4.z};
            float m = sc[0];
            #pragma unroll
            for (int i = 0; i < 9; ++i) m = fmaxf(fmaxf(m, sc[2*i+1]), sc[2*i+2]);
            float sum = 0.f;
            #pragma unroll
            for (int i = 0; i < T_SZ; ++i) sum = fmaf(__expf(sc[i] - m), texp[i], sum);
            score = m + __logf(sum) + em_cur;
        }
        em_cur = em_nxt;
        buf ^= 1;
    }

    if (act) sbuf[0][bl][j] = score + end_t[j];
    __syncthreads();
    if (act && j == 0) {
        float m = -1e30f;
        #pragma unroll
        for (int i = 0; i < T_SZ; ++i) m = fmaxf(m, sbuf[0][bl][i]);
        float sum = 0.f;
        #pragma unroll
        for (int i = 0; i < T_SZ; ++i) sum += __expf(sbuf[0][bl][i] - m);
        atomicAdd(out, num[b] - (m + __logf(sum)));
    }
}

// ---------------------------------------------------------------------------
extern "C" void kernel_launch(void* const* d_in, const int* in_sizes, int n_in,
                              void* d_out, int out_size, void* d_ws, size_t ws_size,
                              hipStream_t stream) {
    const float* x       = (const float*)d_in[0];
    const int*   tags    = (const int*)  d_in[1];
    const float* w_ih_f  = (const float*)d_in[2];
    const float* w_hh_f  = (const float*)d_in[3];
    const float* b_ih_f  = (const float*)d_in[4];
    const float* b_hh_f  = (const float*)d_in[5];
    const float* w_ih_b  = (const float*)d_in[6];
    const float* w_hh_b  = (const float*)d_in[7];
    const float* b_ih_b  = (const float*)d_in[8];
    const float* b_hh_b  = (const float*)d_in[9];
    const float* W_tag   = (const float*)d_in[10];
    const float* b_tag   = (const float*)d_in[11];
    const float* start_t = (const float*)d_in[12];
    const float* end_t   = (const float*)d_in[13];
    const float* trans   = (const float*)d_in[14];

    float* ws = (float*)d_ws;
    float* xf  = ws;                         // 13,107,200 fl (becomes hf in-place)
    float* xb  = xf + 13107200;              // 13,107,200 fl (becomes hb in-place)
    float* em  = xb + 13107200;              //  2,490,368 fl
    float* num = em + 2490368;               //        256 fl   (~114.8 MB total)

    k1_inproj<<<2048, 256, 0, stream>>>(x, w_ih_f, b_ih_f, w_ih_b, b_ih_b, xf, xb);
    k2_rnn   <<<512, 128, 0, stream>>>(w_hh_f, b_hh_f, w_hh_b, b_hh_b, xf, xb);
    k4_emis  <<<2048, 256, 0, stream>>>(xf, xb, W_tag, b_tag, em);
    k5_numer <<<256, 64, 0, stream>>>(tags, em, trans, start_t, end_t, num);
    hipMemsetAsync(d_out, 0, sizeof(float), stream);
    k6_crf   <<<86, 64, 0, stream>>>(em, trans, start_t, end_t, num, (float*)d_out);
}